// Round 6
// baseline (4373.709 us; speedup 1.0000x reference)
//
#include <hip/hip_runtime.h>
#include <math.h>

#define NB 32      // batch
#define NT 12      // time steps
#define NN 307     // nodes
#define NE 10      // embedding dim
#define NH 64      // hidden
#define NCIN 65    // 1 + H
#define NO2 128    // 2H
#define BG 16      // batches per einsum block

__device__ __forceinline__ float sigmoidf_(float x) {
    return 1.0f / (1.0f + __expf(-x));
}

// ---------------- precompute ----------------

__global__ void mg_ne0(const float* __restrict__ src,
                       const float* __restrict__ node_emb,
                       const float* __restrict__ tid_emb,
                       const float* __restrict__ dow_emb,
                       const float* __restrict__ hol_emb,
                       const float* __restrict__ hop_w,
                       const float* __restrict__ hop_b,
                       float* __restrict__ ne0)
{
    int idx = blockIdx.x * blockDim.x + threadIdx.x;
    const int total = NB * NT * NN;
    if (idx >= total) return;
    int n = idx % NN;
    const float* s = src + (size_t)idx * 5;
    int ti = (int)(s[1] * 288.0f); ti = ti < 0 ? 0 : (ti > 287 ? 287 : ti);
    int dw = (int)s[2];            dw = dw < 0 ? 0 : (dw > 6 ? 6 : dw);
    int hl = (int)s[3];            hl = hl < 0 ? 0 : (hl > 1 ? 1 : hl);
    float hop = s[4];
    float* o = ne0 + (size_t)idx * NE;
    #pragma unroll
    for (int e = 0; e < NE; ++e) {
        float v = node_emb[n*NE+e] * tid_emb[ti*NE+e] * dow_emb[dw*NE+e] * hol_emb[hl*NE+e];
        o[e] = v * (hop * hop_w[e] + hop_b[e]);
    }
}

__global__ void mg_weff(const float* __restrict__ node_emb,
                        const float* __restrict__ gw, const float* __restrict__ gb,
                        const float* __restrict__ uw, const float* __restrict__ ub,
                        float* __restrict__ weff_g, float* __restrict__ beff_g,
                        float* __restrict__ weff_u, float* __restrict__ beff_u)
{
    const int NG  = 3*NN*2*NCIN*NO2;
    const int NU  = 3*NN*2*NCIN*NH;
    const int NBG = 3*NN*NO2;
    const int NBU = 3*NN*NH;
    int total = NG + NU + NBG + NBU;
    for (int idx = blockIdx.x*blockDim.x + threadIdx.x; idx < total;
         idx += gridDim.x*blockDim.x) {
        if (idx < NG) {
            int j = idx;
            int o = j & (NO2-1); j >>= 7;
            int i = j % NCIN;    j /= NCIN;
            int k = j & 1;       j >>= 1;
            int n = j % NN;      int c = j / NN;
            float a = 0.f;
            #pragma unroll
            for (int e = 0; e < NE; ++e)
                a += node_emb[n*NE+e] * gw[(((c*NE+e)*2+k)*NCIN+i)*NO2 + o];
            weff_g[idx] = a;
        } else if (idx < NG + NU) {
            int j = idx - NG; int jo = j;
            int o = j & (NH-1); j >>= 6;
            int i = j % NCIN;   j /= NCIN;
            int k = j & 1;      j >>= 1;
            int n = j % NN;     int c = j / NN;
            float a = 0.f;
            #pragma unroll
            for (int e = 0; e < NE; ++e)
                a += node_emb[n*NE+e] * uw[(((c*NE+e)*2+k)*NCIN+i)*NH + o];
            weff_u[jo] = a;
        } else if (idx < NG + NU + NBG) {
            int j = idx - NG - NU;
            int o = j & (NO2-1);
            int n = (j >> 7) % NN; int c = (j >> 7) / NN;
            float a = 0.f;
            #pragma unroll
            for (int e = 0; e < NE; ++e)
                a += node_emb[n*NE+e] * gb[(c*NE+e)*NO2 + o];
            beff_g[j] = a;
        } else {
            int j = idx - NG - NU - NBG;
            int o = j & (NH-1);
            int n = (j >> 6) % NN; int c = (j >> 6) / NN;
            float a = 0.f;
            #pragma unroll
            for (int e = 0; e < NE; ++e)
                a += node_emb[n*NE+e] * ub[(c*NE+e)*NH + o];
            beff_u[j] = a;
        }
    }
}

__global__ void mg_zero(float* __restrict__ p, int count) {
    int idx = blockIdx.x * blockDim.x + threadIdx.x;
    if (idx < count) p[idx] = 0.0f;
}

// ---------------- per-cell kernels ----------------

// A: build cat = [x, state], run small MLP -> nv
__global__ __launch_bounds__(64) void mg_a(
    const float* __restrict__ state,
    const float* __restrict__ xptr, int xbs, int xns,
    const float* __restrict__ ne0t,
    const float* __restrict__ w1, const float* __restrict__ b1,
    const float* __restrict__ w2, const float* __restrict__ b2,
    const float* __restrict__ w3, const float* __restrict__ b3,
    float* __restrict__ cat, float* __restrict__ nvout)
{
    int bn = blockIdx.x;
    int b = bn / NN, n = bn % NN;
    int t = threadIdx.x;
    __shared__ float sc[NCIN];
    __shared__ float sh1[16];
    __shared__ float sh2[2];
    float st = state[(size_t)bn*NH + t];
    sc[1+t] = st;
    cat[(size_t)bn*NCIN + 1 + t] = st;
    if (t == 0) {
        float xv = xptr[(size_t)b*xbs + (size_t)n*xns];
        sc[0] = xv;
        cat[(size_t)bn*NCIN] = xv;
    }
    __syncthreads();
    if (t < 16) {
        float a = b1[t];
        const float* w = w1 + t*NCIN;
        #pragma unroll
        for (int i = 0; i < NCIN; ++i) a += sc[i] * w[i];
        sh1[t] = sigmoidf_(a);
    }
    __syncthreads();
    if (t < 2) {
        float a = b2[t];
        const float* w = w2 + t*16;
        #pragma unroll
        for (int i = 0; i < 16; ++i) a += sh1[i] * w[i];
        sh2[t] = sigmoidf_(a);
    }
    __syncthreads();
    if (t < NE) {
        float xe = sh2[0]*w3[t*2] + sh2[1]*w3[t*2+1] + b3[t];
        nvout[(size_t)bn*NE + t] =
            tanhf(ne0t[(size_t)b*NT*NN*NE + n*NE + t] * xe);
    }
}

// B: g row + d
__global__ __launch_bounds__(64) void mg_b(
    const float* __restrict__ nv, float* __restrict__ g, float* __restrict__ dd)
{
    int bn = blockIdx.x;
    int b = bn / NN;
    int t = threadIdx.x;
    __shared__ float snv[NE];
    if (t < NE) snv[t] = nv[(size_t)bn*NE + t];
    __syncthreads();
    float v0=snv[0],v1=snv[1],v2=snv[2],v3=snv[3],v4=snv[4],
          v5=snv[5],v6=snv[6],v7=snv[7],v8=snv[8],v9=snv[9];
    float sum = 0.0f;
    for (int m = t; m < NN; m += 64) {
        const float* q = nv + ((size_t)b*NN + m)*NE;
        float dot = v0*q[0]+v1*q[1]+v2*q[2]+v3*q[3]+v4*q[4]
                  + v5*q[5]+v6*q[6]+v7*q[7]+v8*q[8]+v9*q[9];
        float gv = fmaxf(dot, 0.0f);
        g[(size_t)bn*NN + m] = gv;
        sum += gv;
    }
    #pragma unroll
    for (int off = 32; off > 0; off >>= 1) sum += __shfl_down(sum, off, 64);
    if (t == 0) dd[bn] = 1.0f / sqrtf(sum);
}

// C: Lx[b,n,i] = d[n] * sum_m g[n,m]*d[m]*cat[m,i]  (16 rows per block)
#define GR 16
__global__ __launch_bounds__(256) void mg_c(
    const float* __restrict__ g, const float* __restrict__ dd,
    const float* __restrict__ cat, float* __restrict__ lx)
{
    int blk = blockIdx.x;
    int b = blk / 20;
    int n0 = (blk % 20) * GR;
    int t = threadIdx.x;
    int j = t >> 4;
    int i0 = t & 15;
    __shared__ float catc[64][66];
    __shared__ float dc[64];
    __shared__ float gj[GR][64];
    float acc0=0.f, acc1=0.f, acc2=0.f, acc3=0.f, acc4=0.f;
    for (int m0 = 0; m0 < NN; m0 += 64) {
        for (int idx = t; idx < 64*65; idx += 256) {
            int ml = idx / 65, ii = idx % 65;
            int m = m0 + ml;
            catc[ml][ii] = (m < NN) ? cat[((size_t)b*NN + m)*NCIN + ii] : 0.f;
        }
        if (t < 64) {
            int m = m0 + t;
            dc[t] = (m < NN) ? dd[b*NN + m] : 0.f;
        }
        for (int idx = t; idx < GR*64; idx += 256) {
            int jj = idx >> 6, ml = idx & 63;
            int row = n0 + jj, m = m0 + ml;
            gj[jj][ml] = (row < NN && m < NN)
                       ? g[((size_t)b*NN + row)*NN + m] : 0.f;
        }
        __syncthreads();
        #pragma unroll 4
        for (int ml = 0; ml < 64; ++ml) {
            float coef = gj[j][ml] * dc[ml];
            acc0 += coef * catc[ml][i0];
            acc1 += coef * catc[ml][i0+16];
            acc2 += coef * catc[ml][i0+32];
            acc3 += coef * catc[ml][i0+48];
            acc4 += coef * catc[ml][64];
        }
        __syncthreads();
    }
    int row = n0 + j;
    if (row < NN) {
        float dn = dd[b*NN + row];
        size_t base = ((size_t)b*NN + row)*NCIN;
        lx[base + i0]      = dn*acc0;
        lx[base + i0+16]   = dn*acc1;
        lx[base + i0+32]   = dn*acc2;
        lx[base + i0+48]   = dn*acc3;
        if (i0 == 0) lx[base + 64] = dn*acc4;
    }
}

// D1: gates einsum -> zr=sigmoid(.); fused cand = [x, z*state] and MLP_u -> nv
__global__ __launch_bounds__(256) void mg_d1(
    const float* __restrict__ cat1, const float* __restrict__ lxb,
    const float* __restrict__ weff, const float* __restrict__ beff,
    const float* __restrict__ state,
    const float* __restrict__ xptr, int xbs, int xns,
    const float* __restrict__ ne0t,
    const float* __restrict__ u1w, const float* __restrict__ u1b,
    const float* __restrict__ u2w, const float* __restrict__ u2b,
    const float* __restrict__ u3w, const float* __restrict__ u3b,
    float* __restrict__ zr, float* __restrict__ cat2, float* __restrict__ nvout)
{
    int n = blockIdx.x >> 1;
    int b0 = (blockIdx.x & 1) * BG;
    int t = threadIdx.x;
    __shared__ float sin_[130][20];   // [i][b-local], padded stride 20 (16B-aligned rows)
    __shared__ float szr[BG][NO2];
    __shared__ float scand[BG][NCIN];
    __shared__ float sh1[BG][16];
    __shared__ float sh2[BG][2];
    for (int idx = t; idx < 130*BG; idx += 256) {
        int i = idx % 130, bb = idx / 130;
        int b = b0 + bb;
        float v = (i < NCIN) ? cat1[((size_t)b*NN+n)*NCIN + i]
                             : lxb[((size_t)b*NN+n)*NCIN + (i-NCIN)];
        sin_[i][bb] = v;
    }
    __syncthreads();
    int o = t & (NO2-1);
    int bs = t >> 7;   // 0..1 -> 8 batches each
    float acc[8];
    float bv = beff[n*NO2 + o];
    #pragma unroll
    for (int u = 0; u < 8; ++u) acc[u] = bv;
    const float* w0 = weff + (size_t)n * 2*NCIN*NO2;
    for (int i = 0; i < 130; ++i) {
        float w = w0[i*NO2 + o];
        const float4* s4 = (const float4*)&sin_[i][bs*8];
        float4 a = s4[0], c = s4[1];
        acc[0] += a.x*w; acc[1] += a.y*w; acc[2] += a.z*w; acc[3] += a.w*w;
        acc[4] += c.x*w; acc[5] += c.y*w; acc[6] += c.z*w; acc[7] += c.w*w;
    }
    #pragma unroll
    for (int u = 0; u < 8; ++u) {
        int bb = bs*8 + u;
        float zv = sigmoidf_(acc[u]);
        zr[((size_t)(b0+bb)*NN+n)*NO2 + o] = zv;
        szr[bb][o] = zv;
    }
    __syncthreads();
    for (int idx = t; idx < BG*NCIN; idx += 256) {
        int bb = idx / NCIN, i = idx % NCIN;
        int b = b0 + bb;
        float v;
        if (i == 0) v = xptr[(size_t)b*xbs + (size_t)n*xns];
        else        v = szr[bb][i-1] * state[((size_t)b*NN+n)*NH + (i-1)];
        scand[bb][i] = v;
        cat2[((size_t)b*NN+n)*NCIN + i] = v;
    }
    __syncthreads();
    {
        int bb = t >> 4, j = t & 15;
        float a = u1b[j];
        const float* w = u1w + j*NCIN;
        #pragma unroll
        for (int i = 0; i < NCIN; ++i) a += scand[bb][i] * w[i];
        sh1[bb][j] = sigmoidf_(a);
    }
    __syncthreads();
    if (t < BG*2) {
        int bb = t >> 1, j = t & 1;
        float a = u2b[j];
        const float* w = u2w + j*16;
        #pragma unroll
        for (int i = 0; i < 16; ++i) a += sh1[bb][i] * w[i];
        sh2[bb][j] = sigmoidf_(a);
    }
    __syncthreads();
    if (t < BG*NE) {
        int bb = t / NE, e = t % NE;
        int b = b0 + bb;
        float xe = sh2[bb][0]*u3w[e*2] + sh2[bb][1]*u3w[e*2+1] + u3b[e];
        nvout[((size_t)b*NN+n)*NE + e] =
            tanhf(ne0t[(size_t)b*NT*NN*NE + n*NE + e] * xe);
    }
}

// D2: candidate einsum -> hc=tanh(.); GRU update h = r*state + (1-r)*hc
__global__ __launch_bounds__(256) void mg_d2(
    const float* __restrict__ cat2, const float* __restrict__ lxb,
    const float* __restrict__ weff, const float* __restrict__ beff,
    const float* __restrict__ zr,
    float* __restrict__ state, float* __restrict__ outi)
{
    int n = blockIdx.x >> 1;
    int b0 = (blockIdx.x & 1) * BG;
    int t = threadIdx.x;
    __shared__ float sin_[130][20];
    for (int idx = t; idx < 130*BG; idx += 256) {
        int i = idx % 130, bb = idx / 130;
        int b = b0 + bb;
        float v = (i < NCIN) ? cat2[((size_t)b*NN+n)*NCIN + i]
                             : lxb[((size_t)b*NN+n)*NCIN + (i-NCIN)];
        sin_[i][bb] = v;
    }
    __syncthreads();
    int o = t & (NH-1);
    int bs = t >> 6;   // 0..3 -> 4 batches each
    float acc[4];
    float bv = beff[n*NH + o];
    #pragma unroll
    for (int u = 0; u < 4; ++u) acc[u] = bv;
    const float* w0 = weff + (size_t)n * 2*NCIN*NH;
    for (int i = 0; i < 130; ++i) {
        float w = w0[i*NH + o];
        const float4* s4 = (const float4*)&sin_[i][bs*4];
        float4 a = s4[0];
        acc[0] += a.x*w; acc[1] += a.y*w; acc[2] += a.z*w; acc[3] += a.w*w;
    }
    #pragma unroll
    for (int u = 0; u < 4; ++u) {
        int b = b0 + bs*4 + u;
        float hc = tanhf(acc[u]);
        size_t sb = ((size_t)b*NN+n)*NH + o;
        float st = state[sb];
        float r = zr[((size_t)b*NN+n)*NO2 + NH + o];
        float h = r*st + (1.0f - r)*hc;
        state[sb] = h;
        if (outi) outi[(size_t)b*2*NN*NH + (size_t)n*NH + o] = h;
    }
}

// skip conv between layers: x2 = conv(out1) + flow
__global__ void mg_conv(
    const float* __restrict__ out1, const float* __restrict__ skip_w,
    const float* __restrict__ skip_b, const float* __restrict__ src,
    float* __restrict__ x2)
{
    int idx = blockIdx.x*blockDim.x + threadIdx.x;
    if (idx >= NB*NT*NN) return;
    int n = idx % NN; int r = idx / NN; int o = r % NT; int b = r / NT;
    float acc = skip_b[o];
    #pragma unroll
    for (int c = 0; c < 2; ++c) {
        const float* p = out1 + ((size_t)(b*2+c)*NN + n)*NH;
        const float* w = skip_w + (o*2+c)*NH;
        #pragma unroll
        for (int k = 0; k < NH; ++k) acc += p[k]*w[k];
    }
    x2[idx] = acc + src[(size_t)idx*5];
}

// layernorm over concat(out1,out2) + end conv -> output
__global__ __launch_bounds__(128) void mg_final(
    const float* __restrict__ out1, const float* __restrict__ out2,
    const float* __restrict__ ln_g, const float* __restrict__ ln_b,
    const float* __restrict__ end_w, const float* __restrict__ end_b,
    float* __restrict__ dout)
{
    int bn = blockIdx.x;
    int b = bn / NN, n = bn % NN;
    int t = threadIdx.x;
    __shared__ float snorm[2][NO2];
    __shared__ float red[2];
    for (int c = 0; c < 2; ++c) {
        size_t base = ((size_t)(b*2+c)*NN + n)*NH;
        float p = (t < NH) ? out1[base + t] : out2[base + (t - NH)];
        float s = p;
        #pragma unroll
        for (int off = 32; off > 0; off >>= 1) s += __shfl_down(s, off, 64);
        if ((t & 63) == 0) red[t >> 6] = s;
        __syncthreads();
        float m = (red[0] + red[1]) * (1.0f/128.0f);
        __syncthreads();
        float df = p - m;
        float s2 = df*df;
        #pragma unroll
        for (int off = 32; off > 0; off >>= 1) s2 += __shfl_down(s2, off, 64);
        if ((t & 63) == 0) red[t >> 6] = s2;
        __syncthreads();
        float v = (red[0] + red[1]) * (1.0f/128.0f);
        snorm[c][t] = df / sqrtf(v + 1e-12f) * ln_g[t] + ln_b[t];
        __syncthreads();
    }
    if (t < NT) {
        float a = end_b[t];
        const float* w = end_w + t*2*NO2;
        for (int c = 0; c < 2; ++c)
            for (int j = 0; j < NO2; ++j)
                a += snorm[c][j] * w[c*NO2 + j];
        dout[(size_t)(b*NT + t)*NN + n] = a;
    }
}

// ---------------- host ----------------

extern "C" void kernel_launch(void* const* d_in, const int* in_sizes, int n_in,
                              void* d_out, int out_size, void* d_ws, size_t ws_size,
                              hipStream_t stream)
{
    const float* src      = (const float*)d_in[0];
    const float* node_emb = (const float*)d_in[1];
    const float* tid_emb  = (const float*)d_in[2];
    const float* dow_emb  = (const float*)d_in[3];
    const float* hol_emb  = (const float*)d_in[4];
    const float* hop_w    = (const float*)d_in[5];
    const float* hop_b    = (const float*)d_in[6];
    const float* gw  = (const float*)d_in[7];
    const float* gb  = (const float*)d_in[8];
    const float* g1w = (const float*)d_in[9];
    const float* g1b = (const float*)d_in[10];
    const float* g2w = (const float*)d_in[11];
    const float* g2b = (const float*)d_in[12];
    const float* g3w = (const float*)d_in[13];
    const float* g3b = (const float*)d_in[14];
    const float* uw  = (const float*)d_in[15];
    const float* ub  = (const float*)d_in[16];
    const float* u1w = (const float*)d_in[17];
    const float* u1b = (const float*)d_in[18];
    const float* u2w = (const float*)d_in[19];
    const float* u2b = (const float*)d_in[20];
    const float* u3w = (const float*)d_in[21];
    const float* u3b = (const float*)d_in[22];
    const float* skip_w = (const float*)d_in[23];
    const float* skip_b = (const float*)d_in[24];
    const float* ln_g = (const float*)d_in[25];
    const float* ln_b = (const float*)d_in[26];
    const float* end_w = (const float*)d_in[27];
    const float* end_b = (const float*)d_in[28];
    float* dout = (float*)d_out;

    float* ws = (float*)d_ws;
    size_t off = 0;
    float* weff_g = ws + off; off += (size_t)3*NN*2*NCIN*NO2;  // 15.3M
    float* weff_u = ws + off; off += (size_t)3*NN*2*NCIN*NH;   // 7.7M
    float* beff_g = ws + off; off += (size_t)3*NN*NO2;
    float* beff_u = ws + off; off += (size_t)3*NN*NH;
    float* ne0    = ws + off; off += (size_t)NB*NT*NN*NE;
    float* st     = ws + off; off += (size_t)2*NB*NN*NH;
    float* cat1   = ws + off; off += (size_t)NB*NN*NCIN;
    float* cat2   = ws + off; off += (size_t)NB*NN*NCIN;
    float* nv     = ws + off; off += (size_t)NB*NN*NE;
    float* gbuf   = ws + off; off += (size_t)NB*NN*NN;         // 3.0M
    float* dd     = ws + off; off += (size_t)NB*NN;
    float* lx     = ws + off; off += (size_t)NB*NN*NCIN;
    float* zr     = ws + off; off += (size_t)NB*NN*NO2;
    float* out1   = ws + off; off += (size_t)NB*2*NN*NH;
    float* out2   = ws + off; off += (size_t)NB*2*NN*NH;
    float* x2     = ws + off; off += (size_t)NB*NT*NN;

    mg_ne0<<<(NB*NT*NN + 255)/256, 256, 0, stream>>>(
        src, node_emb, tid_emb, dow_emb, hol_emb, hop_w, hop_b, ne0);
    mg_weff<<<4096, 256, 0, stream>>>(
        node_emb, gw, gb, uw, ub, weff_g, beff_g, weff_u, beff_u);

    const int stcount = 2*NB*NN*NH;
    mg_zero<<<(stcount+255)/256, 256, 0, stream>>>(st, stcount);

    auto cell = [&](int c, int t, const float* xptr, int xbs, int xns,
                    float* state, float* outi) {
        const float* ne0t = ne0 + (size_t)t*NN*NE;
        mg_a<<<NB*NN, 64, 0, stream>>>(state, xptr, xbs, xns, ne0t,
            g1w + c*16*NCIN, g1b + c*16, g2w + c*2*16, g2b + c*2,
            g3w + c*NE*2, g3b + c*NE, cat1, nv);
        mg_b<<<NB*NN, 64, 0, stream>>>(nv, gbuf, dd);
        mg_c<<<NB*20, 256, 0, stream>>>(gbuf, dd, cat1, lx);
        mg_d1<<<NN*(NB/BG), 256, 0, stream>>>(cat1, lx,
            weff_g + (size_t)c*NN*2*NCIN*NO2, beff_g + (size_t)c*NN*NO2,
            state, xptr, xbs, xns, ne0t,
            u1w + c*16*NCIN, u1b + c*16, u2w + c*2*16, u2b + c*2,
            u3w + c*NE*2, u3b + c*NE, zr, cat2, nv);
        mg_b<<<NB*NN, 64, 0, stream>>>(nv, gbuf, dd);
        mg_c<<<NB*20, 256, 0, stream>>>(gbuf, dd, cat2, lx);
        mg_d2<<<NN*(NB/BG), 256, 0, stream>>>(cat2, lx,
            weff_u + (size_t)c*NN*2*NCIN*NH, beff_u + (size_t)c*NN*NH,
            zr, state, outi);
    };

    // layer 1 (cell 0, single state chain)
    for (int t = 0; t < NT; ++t) {
        float* outi = (t >= NT-2) ? (out1 + (size_t)(t-(NT-2))*NN*NH) : nullptr;
        cell(0, t, src + (size_t)t*NN*5, NT*NN*5, 5, st, outi);
    }
    mg_conv<<<(NB*NT*NN+255)/256, 256, 0, stream>>>(out1, skip_w, skip_b, src, x2);
    mg_zero<<<(stcount+255)/256, 256, 0, stream>>>(st, stcount);
    // layer 2 (cells 1,2 alternating, two state chains)
    for (int t = 0; t < NT; ++t) {
        int c = 1 + (t & 1);
        float* state = st + (size_t)(t & 1)*NB*NN*NH;
        float* outi = (t >= NT-2) ? (out2 + (size_t)(t-(NT-2))*NN*NH) : nullptr;
        cell(c, t, x2 + (size_t)t*NN, NT*NN, 1, state, outi);
    }
    mg_final<<<NB*NN, 128, 0, stream>>>(out1, out2, ln_g, ln_b, end_w, end_b, dout);
}